// Round 12
// baseline (71.199 us; speedup 1.0000x reference)
//
#include <hip/hip_runtime.h>
#include <stdint.h>

#define BB 256
#define CC 64
#define CVV 4
#define LL 2048
#define NR (CC + CVV)   // 68 rows per block (= per batch)

// LDS-only barrier: orders ds ops across waves WITHOUT draining vmcnt.
#define SBAR_LDS() do { \
    asm volatile("s_waitcnt lgkmcnt(0)" ::: "memory"); \
    __builtin_amdgcn_s_barrier(); \
    __builtin_amdgcn_sched_barrier(0); \
  } while (0)

__device__ __forceinline__ void ce_desc(unsigned long long* key, int i, int j,
                                        bool descBlk) {
  unsigned long long a = key[i], c = key[j];
  bool sw = descBlk ? (a < c) : (a > c);
  if (sw) { key[i] = c; key[j] = a; }
}

// ---------------------------------------------------------------------------
// One block per batch (256 blocks = 1/CU, 512 threads = 8 waves).
// Phase 1 (cooperative): bitonic argsort of rand_f (composite keys
//   ord(rand_f)<<32 | (L-1-idx), wave-segment optimized, LDS-only barriers).
// Phase 2 (wave-autonomous): each wave owns rows [row0, row0+nrows) of the
//   batch (waves 0-3: 9 rows, waves 4-7: 8) with a PRIVATE 2-slot LDS double
//   buffer and double-buffered named register sets a0..7 / b0..7. Every wave
//   holds the full permutation for its lane's 32 output positions in 8 named
//   int4s (s0..s7), read once from the sorted keys. After ONE post-sort
//   barrier there is no cross-wave sync at all: waves free-run, so DS-phase
//   waves and VMEM-phase waves overlap on the CU and the HBM stream stays
//   fed (no lockstep bursts). Same-wave LDS RAW is DS-pipe-ordered; the
//   compiler emits precise per-register vmcnt for the staging loads.
// ---------------------------------------------------------------------------
__global__ __launch_bounds__(512) void trimmer_kernel(
    const float* __restrict__ x, const float* __restrict__ v,
    const void* __restrict__ mask, const float* __restrict__ rnd,
    float* __restrict__ xo, float* __restrict__ vo, float* __restrict__ mo) {
  __shared__ union {
    unsigned long long key[LL];   // 16 KB = wave 0's slots (ring[0..1])
    float ring[16][LL];           // 16 x 8 KB = 128 KB; wave w: slots 2w,2w+1
  } sh;
  __shared__ int wcnt[8];

  const int b = blockIdx.x;
  const int tid = threadIdx.x;
  const int w = tid >> 6;
  const int lane = tid & 63;
  const unsigned* m32 = (const unsigned*)mask;

  // --- scalar-load layout detect (uniform address -> s_load) ---
  unsigned acc = 0;
#pragma unroll
  for (int j = 0; j < 16; ++j) acc |= m32[(size_t)b * 512 + j];
  const bool is_byte = (acc != 0u) && (acc != 1u) && (acc != 0x3F800000u);

  // --- register loads of rand + mask for key build (issued first) ---
  float rv[4]; unsigned mw[4];
#pragma unroll
  for (int k = 0; k < 4; ++k) {
    const int l = tid + 512 * k;
    rv[k] = rnd[(size_t)b * LL + l];
    mw[k] = is_byte ? m32[(size_t)b * 512 + (l >> 2)]
                    : m32[(size_t)b * LL + l];
  }

  const float* const xs = x + (size_t)b * CC * LL;
  const float* const vs = v + (size_t)b * CVV * LL;
  float* const xd = xo + (size_t)b * CC * LL;
  float* const vd = vo + (size_t)b * CVV * LL;

#define SRCROW(rr) ((rr) < CC ? xs + (size_t)(rr) * LL \
                              : vs + (size_t)((rr) - CC) * LL)
#define DSTROW(rr) ((rr) < CC ? xd + (size_t)(rr) * LL \
                              : vd + (size_t)((rr) - CC) * LL)

  // wave-owned row range: waves 0-3 get 9 rows, waves 4-7 get 8
  const int row0 = (w < 4) ? 9 * w : 36 + 8 * (w - 4);
  const int nrows = (w < 4) ? 9 : 8;
  const int slotA = 2 * w, slotB = 2 * w + 1;

#define LOADSET(A0,A1,A2,A3,A4,A5,A6,A7, rr) do { \
    const float4* _s = (const float4*)SRCROW(rr); \
    A0 = _s[lane];       A1 = _s[lane + 64];  A2 = _s[lane + 128]; \
    A3 = _s[lane + 192]; A4 = _s[lane + 256]; A5 = _s[lane + 320]; \
    A6 = _s[lane + 384]; A7 = _s[lane + 448]; \
  } while (0)

  // --- prologue: rows row0, row0+1 into named reg sets (flow under sort) ---
  float4 a0, a1, a2, a3, a4, a5, a6, a7;
  float4 b0, b1, b2, b3, b4, b5, b6, b7;
  LOADSET(a0,a1,a2,a3,a4,a5,a6,a7, row0);
  LOADSET(b0,b1,b2,b3,b4,b5,b6,b7, row0 + 1);

  // --- build composite keys ---
  const int sh8 = 8 * (tid & 3);
  int local = 0;
#pragma unroll
  for (int k = 0; k < 4; ++k) {
    const int l = tid + 512 * k;
    const bool m = is_byte ? (((mw[k] >> sh8) & 0xFFu) != 0u) : (mw[k] != 0u);
    float rf = m ? -1.0f : rv[k];
    unsigned u = __float_as_uint(rf);
    u = (u & 0x80000000u) ? ~u : (u | 0x80000000u);  // order-preserving map
    sh.key[l] = ((unsigned long long)u << 32) | (unsigned)(LL - 1 - l);
    local += m ? 1 : 0;
  }
#pragma unroll
  for (int off = 32; off > 0; off >>= 1) local += __shfl_down(local, off, 64);
  if (lane == 0) wcnt[w] = local;
  SBAR_LDS();

  // --- bitonic sort, descending; wave w owns key[w*256 .. w*256+255] ---
  for (int size = 2; size <= 256; size <<= 1) {
    for (int stride = size >> 1; stride > 0; stride >>= 1) {
#pragma unroll
      for (int pp = 0; pp < 2; ++pp) {
        int p = w * 128 + pp * 64 + lane;
        int i = ((p & ~(stride - 1)) << 1) | (p & (stride - 1));
        ce_desc(sh.key, i, i + stride, (i & size) == 0);
      }
      __builtin_amdgcn_wave_barrier();
    }
  }
  SBAR_LDS();
  for (int size = 512; size <= 2048; size <<= 1) {
    for (int stride = size >> 1; stride >= 256; stride >>= 1) {
      for (int t = tid; t < LL / 2; t += 512) {
        int i = ((t & ~(stride - 1)) << 1) | (t & (stride - 1));
        ce_desc(sh.key, i, i + stride, (i & size) == 0);
      }
      SBAR_LDS();
    }
    for (int stride = 128; stride > 0; stride >>= 1) {
#pragma unroll
      for (int pp = 0; pp < 2; ++pp) {
        int p = w * 128 + pp * 64 + lane;
        int i = ((p & ~(stride - 1)) << 1) | (p & (stride - 1));
        ce_desc(sh.key, i, i + stride, (i & size) == 0);
      }
      __builtin_amdgcn_wave_barrier();
    }
    SBAR_LDS();
  }

  // --- every wave extracts the FULL per-lane perm (32 entries = 8 int4) ---
  const int cnt = wcnt[0] + wcnt[1] + wcnt[2] + wcnt[3] +
                  wcnt[4] + wcnt[5] + wcnt[6] + wcnt[7];
  const int maxlen = cnt > 1 ? cnt : 1;              // jnp.maximum(count, 1)
  const unsigned ordNeg1 = ~__float_as_uint(-1.0f);  // ord(-1.0)

#define PK(kk, jj) ((int)((LL - 1) - (unsigned)((kk) & 0xFFFFFFFFull)) \
    | ((((unsigned)((kk) >> 32)) == ordNeg1) ? (1 << 11) : 0) \
    | (((jj) < maxlen) ? (1 << 12) : 0))
#define EXTRACT(q, S) do { \
    const int _j = (q) * 256 + lane * 4; \
    const unsigned long long* _kp = &sh.key[_j]; \
    unsigned long long _k0 = _kp[0], _k1 = _kp[1]; \
    unsigned long long _k2 = _kp[2], _k3 = _kp[3]; \
    S = make_int4(PK(_k0, _j), PK(_k1, _j + 1), \
                  PK(_k2, _j + 2), PK(_k3, _j + 3)); \
  } while (0)

  int4 s0, s1, s2, s3, s4, s5, s6, s7;
  EXTRACT(0, s0); EXTRACT(1, s1); EXTRACT(2, s2); EXTRACT(3, s3);
  EXTRACT(4, s4); EXTRACT(5, s5); EXTRACT(6, s6); EXTRACT(7, s7);

  // --- wave 0 writes mask_t from its perm registers ---
  if (w == 0) {
    float4* mv = (float4*)(mo + (size_t)b * LL);
#define MQ(S, q) do { float4 _m; \
    _m.x = ((S.x & (1<<11)) && (S.x & (1<<12))) ? 1.0f : 0.0f; \
    _m.y = ((S.y & (1<<11)) && (S.y & (1<<12))) ? 1.0f : 0.0f; \
    _m.z = ((S.z & (1<<11)) && (S.z & (1<<12))) ? 1.0f : 0.0f; \
    _m.w = ((S.w & (1<<11)) && (S.w & (1<<12))) ? 1.0f : 0.0f; \
    mv[lane + (q) * 64] = _m; } while (0)
    MQ(s0, 0); MQ(s1, 1); MQ(s2, 2); MQ(s3, 3);
    MQ(s4, 4); MQ(s5, 5); MQ(s6, 6); MQ(s7, 7);
#undef MQ
  }
  SBAR_LDS();  // all key[] reads done; wave 0 may now overwrite ring[0..1]

  // --- wave-autonomous gather: no cross-wave sync from here on ---
#define WSET(slot, A0,A1,A2,A3,A4,A5,A6,A7) do { \
    float4* _d = (float4*)&sh.ring[slot][0]; \
    _d[lane] = A0;       _d[lane + 64] = A1;  _d[lane + 128] = A2; \
    _d[lane + 192] = A3; _d[lane + 256] = A4; _d[lane + 320] = A5; \
    _d[lane + 384] = A6; _d[lane + 448] = A7; \
  } while (0)
#define G1(S, q) do { float4 _o4; \
    _o4.x = (S.x & (1 << 12)) ? _b[S.x & 0x7FF] : 0.0f; \
    _o4.y = (S.y & (1 << 12)) ? _b[S.y & 0x7FF] : 0.0f; \
    _o4.z = (S.z & (1 << 12)) ? _b[S.z & 0x7FF] : 0.0f; \
    _o4.w = (S.w & (1 << 12)) ? _b[S.w & 0x7FF] : 0.0f; \
    _o[lane + (q) * 64] = _o4; } while (0)
#define GSET(slot, rr) do { \
    const float* _b = &sh.ring[slot][0]; \
    float4* _o = (float4*)DSTROW(rr); \
    G1(s0, 0); G1(s1, 1); G1(s2, 2); G1(s3, 3); \
    G1(s4, 4); G1(s5, 5); G1(s6, 6); G1(s7, 7); \
  } while (0)

#pragma unroll 1
  for (int i = 0; i < nrows; i += 2) {
    const int r = row0 + i;
    WSET(slotA, a0,a1,a2,a3,a4,a5,a6,a7);
    if (i + 2 < nrows) LOADSET(a0,a1,a2,a3,a4,a5,a6,a7, r + 2);
    GSET(slotA, r);
    if (i + 1 < nrows) {
      WSET(slotB, b0,b1,b2,b3,b4,b5,b6,b7);
      if (i + 3 < nrows) LOADSET(b0,b1,b2,b3,b4,b5,b6,b7, r + 3);
      GSET(slotB, r + 1);
    }
  }
#undef GSET
#undef G1
#undef WSET
#undef EXTRACT
#undef PK
#undef LOADSET
#undef SRCROW
#undef DSTROW
}

extern "C" void kernel_launch(void* const* d_in, const int* in_sizes, int n_in,
                              void* d_out, int out_size, void* d_ws, size_t ws_size,
                              hipStream_t stream) {
  const float* x    = (const float*)d_in[0];
  const float* v    = (const float*)d_in[1];
  const void*  mask = d_in[2];
  const float* rnd  = (const float*)d_in[3];

  float* xo = (float*)d_out;                  // B*C*L
  float* vo = xo + (size_t)BB * CC * LL;      // B*CV*L
  float* mo = vo + (size_t)BB * CVV * LL;     // B*1*L

  trimmer_kernel<<<BB, 512, 0, stream>>>(x, v, mask, rnd, xo, vo, mo);
}

// Round 13
// 66.398 us; speedup vs baseline: 1.0723x; 1.0723x over previous
//
#include <hip/hip_runtime.h>
#include <stdint.h>

#define BB 256
#define CC 64
#define CVV 4
#define LL 2048
#define NR (CC + CVV)   // 68 rows per block (= per batch)

// LDS-only barrier: orders ds ops across waves WITHOUT draining vmcnt
// (__syncthreads would emit s_waitcnt vmcnt(0) and stall the load stream).
#define SBAR_LDS() do { \
    asm volatile("s_waitcnt lgkmcnt(0)" ::: "memory"); \
    __builtin_amdgcn_s_barrier(); \
    __builtin_amdgcn_sched_barrier(0); \
  } while (0)

__device__ __forceinline__ void ce_desc(unsigned long long* key, int i, int j,
                                        bool descBlk) {
  unsigned long long a = key[i], c = key[j];
  bool sw = descBlk ? (a < c) : (a > c);
  if (sw) { key[i] = c; key[j] = a; }
}

// ---------------------------------------------------------------------------
// One block per batch (256 blocks = 1/CU, 512 threads = 8 waves).
// Phase 1: bitonic argsort of rand_f (composite keys ord(rand_f)<<32 |
//   (L-1-idx), wave-segment optimized, LDS-only barriers). Perm for this
//   thread's 4 output positions -> int4 register; mask_t written directly.
// Phase 2: register-staged gather (named regs a0..a7 - R10's array spilled
//   to scratch), 4-slot LDS ring, two rows per barrier, no vmcnt drain.
// ZERO-TAIL FAST PATH (R13): maxlen = popcount(mask) = cnt, and every output
//   position j >= cnt is zero (keep bit clear). Thread tid owns j=4tid..
//   4tid+3, so waves whose j-range lies beyond cnt (~half, cnt~1024 here)
//   branch to a pure zero-store path with NO ds_reads: halves gather DS
//   issue and bank conflicts; HBM bytes unchanged.
// ---------------------------------------------------------------------------
__global__ __launch_bounds__(512) void trimmer_kernel(
    const float* __restrict__ x, const float* __restrict__ v,
    const void* __restrict__ mask, const float* __restrict__ rnd,
    float* __restrict__ xo, float* __restrict__ vo, float* __restrict__ mo) {
  __shared__ union {
    unsigned long long key[LL];   // 16 KB = ring slots 0-1
    float ring[4][LL];            // 4 x 8 KB = 32 KB
  } sh;
  __shared__ int wcnt[8];

  const int b = blockIdx.x;
  const int tid = threadIdx.x;
  const int w = tid >> 6;
  const int lane = tid & 63;
  const unsigned* m32 = (const unsigned*)mask;

  // --- scalar-load layout detect (uniform address -> s_load) ---
  unsigned acc = 0;
#pragma unroll
  for (int j = 0; j < 16; ++j) acc |= m32[(size_t)b * 512 + j];
  const bool is_byte = (acc != 0u) && (acc != 1u) && (acc != 0x3F800000u);

  // --- register loads of rand + mask for key build ---
  float rv[4]; unsigned mw[4];
#pragma unroll
  for (int k = 0; k < 4; ++k) {
    const int l = tid + 512 * k;
    rv[k] = rnd[(size_t)b * LL + l];
    mw[k] = is_byte ? m32[(size_t)b * 512 + (l >> 2)]
                    : m32[(size_t)b * LL + l];
  }

  const float* const xs = x + (size_t)b * CC * LL;
  const float* const vs = v + (size_t)b * CVV * LL;
  float* const xd = xo + (size_t)b * CC * LL;
  float* const vd = vo + (size_t)b * CVV * LL;

#define SRCROW(rr) ((rr) < CC ? xs + (size_t)(rr) * LL \
                              : vs + (size_t)((rr) - CC) * LL)
#define DSTROW(rr) ((rr) < CC ? xd + (size_t)(rr) * LL \
                              : vd + (size_t)((rr) - CC) * LL)

  // --- prefetch rows 0..7 into NAMED registers (flows under the sort) ---
  float4 a0 = ((const float4*)SRCROW(0))[tid];
  float4 a1 = ((const float4*)SRCROW(1))[tid];
  float4 a2 = ((const float4*)SRCROW(2))[tid];
  float4 a3 = ((const float4*)SRCROW(3))[tid];
  float4 a4 = ((const float4*)SRCROW(4))[tid];
  float4 a5 = ((const float4*)SRCROW(5))[tid];
  float4 a6 = ((const float4*)SRCROW(6))[tid];
  float4 a7 = ((const float4*)SRCROW(7))[tid];

  // --- build composite keys ---
  const int sh8 = 8 * (tid & 3);
  int local = 0;
#pragma unroll
  for (int k = 0; k < 4; ++k) {
    const int l = tid + 512 * k;
    const bool m = is_byte ? (((mw[k] >> sh8) & 0xFFu) != 0u) : (mw[k] != 0u);
    float rf = m ? -1.0f : rv[k];
    unsigned u = __float_as_uint(rf);
    u = (u & 0x80000000u) ? ~u : (u | 0x80000000u);  // order-preserving map
    sh.key[l] = ((unsigned long long)u << 32) | (unsigned)(LL - 1 - l);
    local += m ? 1 : 0;
  }
#pragma unroll
  for (int off = 32; off > 0; off >>= 1) local += __shfl_down(local, off, 64);
  if (lane == 0) wcnt[w] = local;
  SBAR_LDS();

  // --- bitonic sort, descending; wave w owns key[w*256 .. w*256+255] ---
  for (int size = 2; size <= 256; size <<= 1) {
    for (int stride = size >> 1; stride > 0; stride >>= 1) {
#pragma unroll
      for (int pp = 0; pp < 2; ++pp) {
        int p = w * 128 + pp * 64 + lane;
        int i = ((p & ~(stride - 1)) << 1) | (p & (stride - 1));
        ce_desc(sh.key, i, i + stride, (i & size) == 0);
      }
      __builtin_amdgcn_wave_barrier();
    }
  }
  SBAR_LDS();
  for (int size = 512; size <= 2048; size <<= 1) {
    for (int stride = size >> 1; stride >= 256; stride >>= 1) {
      for (int t = tid; t < LL / 2; t += 512) {
        int i = ((t & ~(stride - 1)) << 1) | (t & (stride - 1));
        ce_desc(sh.key, i, i + stride, (i & size) == 0);
      }
      SBAR_LDS();
    }
    for (int stride = 128; stride > 0; stride >>= 1) {
#pragma unroll
      for (int pp = 0; pp < 2; ++pp) {
        int p = w * 128 + pp * 64 + lane;
        int i = ((p & ~(stride - 1)) << 1) | (p & (stride - 1));
        ce_desc(sh.key, i, i + stride, (i & size) == 0);
      }
      __builtin_amdgcn_wave_barrier();
    }
    SBAR_LDS();
  }

  // --- extract perm into registers; write mask_t ---
  const int cnt = wcnt[0] + wcnt[1] + wcnt[2] + wcnt[3] +
                  wcnt[4] + wcnt[5] + wcnt[6] + wcnt[7];
  const int maxlen = cnt > 1 ? cnt : 1;              // jnp.maximum(count, 1)
  const unsigned ordNeg1 = ~__float_as_uint(-1.0f);  // ord(-1.0)
  int sv[4]; float mf[4];
#pragma unroll
  for (int k = 0; k < 4; ++k) {
    const int j = tid * 4 + k;
    unsigned long long k2 = sh.key[j];
    int idx = (LL - 1) - (int)(unsigned)(k2 & 0xFFFFFFFFull);
    bool masked = ((unsigned)(k2 >> 32)) == ordNeg1;
    bool keep = j < maxlen;
    sv[k] = idx | (keep ? (1 << 12) : 0);
    mf[k] = (keep && masked) ? 1.0f : 0.0f;
  }
  const int4 s = make_int4(sv[0], sv[1], sv[2], sv[3]);
  ((float4*)(mo + (size_t)b * LL))[tid] =
      make_float4(mf[0], mf[1], mf[2], mf[3]);
  SBAR_LDS();  // all key[] reads done before ring slots 0,1 get written

  // This thread's j-range is entirely zero iff 4*tid >= maxlen (wave-coherent
  // except one boundary wave): skip ALL ds_reads on that path.
  const bool anykeep = (4 * tid) < maxlen;

#define GATHER1(buf, dst) do { \
    if (anykeep) { \
      float4 o; \
      o.x = (s.x & (1 << 12)) ? (buf)[s.x & 0x7FF] : 0.0f; \
      o.y = (s.y & (1 << 12)) ? (buf)[s.y & 0x7FF] : 0.0f; \
      o.z = (s.z & (1 << 12)) ? (buf)[s.z & 0x7FF] : 0.0f; \
      o.w = (s.w & (1 << 12)) ? (buf)[s.w & 0x7FF] : 0.0f; \
      ((float4*)(dst))[tid] = o; \
    } else { \
      ((float4*)(dst))[tid] = make_float4(0.0f, 0.0f, 0.0f, 0.0f); \
    } \
  } while (0)

  // One pair of rows: ds_write 2 rows from named regs, barrier, reload the
  // same named regs with rows +8, gather+store the 2 rows.
#define PAIR(pp, A, B) do { \
    const int r0 = 2 * (pp), r1 = r0 + 1; \
    const int q0 = (2 * (pp)) & 3, q1 = (2 * (pp) + 1) & 3; \
    ((float4*)&sh.ring[q0][0])[tid] = A; \
    ((float4*)&sh.ring[q1][0])[tid] = B; \
    SBAR_LDS(); \
    if (r0 + 8 < NR) A = ((const float4*)SRCROW(r0 + 8))[tid]; \
    if (r1 + 8 < NR) B = ((const float4*)SRCROW(r1 + 8))[tid]; \
    GATHER1(&sh.ring[q0][0], DSTROW(r0)); \
    GATHER1(&sh.ring[q1][0], DSTROW(r1)); \
  } while (0)

  // 34 pairs: 8 macro-iters x 4 pairs (rows 0..63) + 2 epilogue pairs
#pragma unroll 1
  for (int mi = 0; mi < 8; ++mi) {
    PAIR(mi * 4 + 0, a0, a1);
    PAIR(mi * 4 + 1, a2, a3);
    PAIR(mi * 4 + 2, a4, a5);
    PAIR(mi * 4 + 3, a6, a7);
  }
  PAIR(32, a0, a1);  // rows 64,65 (loaded at pair 28)
  PAIR(33, a2, a3);  // rows 66,67 (loaded at pair 29)
#undef PAIR
#undef GATHER1
#undef SRCROW
#undef DSTROW
}

extern "C" void kernel_launch(void* const* d_in, const int* in_sizes, int n_in,
                              void* d_out, int out_size, void* d_ws, size_t ws_size,
                              hipStream_t stream) {
  const float* x    = (const float*)d_in[0];
  const float* v    = (const float*)d_in[1];
  const void*  mask = d_in[2];
  const float* rnd  = (const float*)d_in[3];

  float* xo = (float*)d_out;                  // B*C*L
  float* vo = xo + (size_t)BB * CC * LL;      // B*CV*L
  float* mo = vo + (size_t)BB * CVV * LL;     // B*1*L

  trimmer_kernel<<<BB, 512, 0, stream>>>(x, v, mask, rnd, xo, vo, mo);
}

// Round 14
// 64.970 us; speedup vs baseline: 1.0959x; 1.0220x over previous
//
#include <hip/hip_runtime.h>
#include <stdint.h>

#define BB 256
#define CC 64
#define CVV 4
#define LL 2048
#define NR (CC + CVV)   // 68 rows per block (= per batch)

// Padded key indexing: one 8B pad per 16 keys spreads the bitonic's
// stride-2^k accesses across banks (stride-1 CE was an 8-way conflict:
// b64 reads 16B/lane apart -> bank 4p%32 -> lanes p,p+8,... collide).
#define KIDX(i) ((i) + ((i) >> 4))

// LDS-only barrier: orders ds ops across waves WITHOUT draining vmcnt
// (__syncthreads would emit s_waitcnt vmcnt(0) and stall the load stream).
#define SBAR_LDS() do { \
    asm volatile("s_waitcnt lgkmcnt(0)" ::: "memory"); \
    __builtin_amdgcn_s_barrier(); \
    __builtin_amdgcn_sched_barrier(0); \
  } while (0)

__device__ __forceinline__ void ce_desc(unsigned long long* key, int i, int j,
                                        bool descBlk) {
  unsigned long long a = key[KIDX(i)], c = key[KIDX(j)];
  bool sw = descBlk ? (a < c) : (a > c);
  if (sw) { key[KIDX(i)] = c; key[KIDX(j)] = a; }
}

// ---------------------------------------------------------------------------
// One block per batch (256 blocks = 1/CU, 512 threads = 8 waves).
// Phase 1: bitonic argsort of rand_f (composite keys ord(rand_f)<<32 |
//   (L-1-idx), wave-segment optimized, LDS-only barriers, PADDED key array).
//   Perm for this thread's 4 output positions -> int4 register; mask_t
//   written directly. Mask layout detect via uniform scalar loads.
// Phase 2: register-staged gather, 16 named float4 regs (A0..A15) loaded for
//   rows 0..15 BEFORE the sort (32 MB chip-wide of HBM work under the sort),
//   8-slot LDS ring (64 KB), FOUR rows per barrier (17 rendezvous, was 34),
//   reload distance 16. No vmcnt drain anywhere in the loop.
//   Quad qq: ds_write rows 4qq..4qq+3 -> SBAR -> reload regs with rows
//   +16 -> gather 4 rows (zero-tail fast path).
//   Ring safety (1 barrier/quad): quad qq writes slots last gathered at
//   quad qq-2; any wave reaching its quad-qq writes has passed BAR(qq-1),
//   which it could only do after finishing its qq-2 gathers -> no overlap.
// ---------------------------------------------------------------------------
__global__ __launch_bounds__(512) void trimmer_kernel(
    const float* __restrict__ x, const float* __restrict__ v,
    const void* __restrict__ mask, const float* __restrict__ rnd,
    float* __restrict__ xo, float* __restrict__ vo, float* __restrict__ mo) {
  __shared__ union {
    unsigned long long key[2176];  // 2048 + 128 pads = 17 KB
    float ring[8][LL];             // 8 x 8 KB = 64 KB
  } sh;
  __shared__ int wcnt[8];

  const int b = blockIdx.x;
  const int tid = threadIdx.x;
  const int w = tid >> 6;
  const int lane = tid & 63;
  const unsigned* m32 = (const unsigned*)mask;

  // --- scalar-load layout detect (uniform address -> s_load) ---
  unsigned acc = 0;
#pragma unroll
  for (int j = 0; j < 16; ++j) acc |= m32[(size_t)b * 512 + j];
  const bool is_byte = (acc != 0u) && (acc != 1u) && (acc != 0x3F800000u);

  // --- register loads of rand + mask for key build (issued first) ---
  float rv[4]; unsigned mw[4];
#pragma unroll
  for (int k = 0; k < 4; ++k) {
    const int l = tid + 512 * k;
    rv[k] = rnd[(size_t)b * LL + l];
    mw[k] = is_byte ? m32[(size_t)b * 512 + (l >> 2)]
                    : m32[(size_t)b * LL + l];
  }

  const float* const xs = x + (size_t)b * CC * LL;
  const float* const vs = v + (size_t)b * CVV * LL;
  float* const xd = xo + (size_t)b * CC * LL;
  float* const vd = vo + (size_t)b * CVV * LL;

#define SRCROW(rr) ((rr) < CC ? xs + (size_t)(rr) * LL \
                              : vs + (size_t)((rr) - CC) * LL)
#define DSTROW(rr) ((rr) < CC ? xd + (size_t)(rr) * LL \
                              : vd + (size_t)((rr) - CC) * LL)

  // --- prefetch rows 0..15 into NAMED registers (flows under the sort) ---
  float4 A0  = ((const float4*)SRCROW(0))[tid];
  float4 A1  = ((const float4*)SRCROW(1))[tid];
  float4 A2  = ((const float4*)SRCROW(2))[tid];
  float4 A3  = ((const float4*)SRCROW(3))[tid];
  float4 A4  = ((const float4*)SRCROW(4))[tid];
  float4 A5  = ((const float4*)SRCROW(5))[tid];
  float4 A6  = ((const float4*)SRCROW(6))[tid];
  float4 A7  = ((const float4*)SRCROW(7))[tid];
  float4 A8  = ((const float4*)SRCROW(8))[tid];
  float4 A9  = ((const float4*)SRCROW(9))[tid];
  float4 A10 = ((const float4*)SRCROW(10))[tid];
  float4 A11 = ((const float4*)SRCROW(11))[tid];
  float4 A12 = ((const float4*)SRCROW(12))[tid];
  float4 A13 = ((const float4*)SRCROW(13))[tid];
  float4 A14 = ((const float4*)SRCROW(14))[tid];
  float4 A15 = ((const float4*)SRCROW(15))[tid];
  asm volatile("" ::: "memory");  // loads may not sink below this point

  // --- build composite keys ---
  const int sh8 = 8 * (tid & 3);
  int local = 0;
#pragma unroll
  for (int k = 0; k < 4; ++k) {
    const int l = tid + 512 * k;
    const bool m = is_byte ? (((mw[k] >> sh8) & 0xFFu) != 0u) : (mw[k] != 0u);
    float rf = m ? -1.0f : rv[k];
    unsigned u = __float_as_uint(rf);
    u = (u & 0x80000000u) ? ~u : (u | 0x80000000u);  // order-preserving map
    sh.key[KIDX(l)] = ((unsigned long long)u << 32) | (unsigned)(LL - 1 - l);
    local += m ? 1 : 0;
  }
#pragma unroll
  for (int off = 32; off > 0; off >>= 1) local += __shfl_down(local, off, 64);
  if (lane == 0) wcnt[w] = local;
  SBAR_LDS();

  // --- bitonic sort, descending; wave w owns key[w*256 .. w*256+255] ---
  for (int size = 2; size <= 256; size <<= 1) {
    for (int stride = size >> 1; stride > 0; stride >>= 1) {
#pragma unroll
      for (int pp = 0; pp < 2; ++pp) {
        int p = w * 128 + pp * 64 + lane;
        int i = ((p & ~(stride - 1)) << 1) | (p & (stride - 1));
        ce_desc(sh.key, i, i + stride, (i & size) == 0);
      }
      __builtin_amdgcn_wave_barrier();
    }
  }
  SBAR_LDS();
  for (int size = 512; size <= 2048; size <<= 1) {
    for (int stride = size >> 1; stride >= 256; stride >>= 1) {
      for (int t = tid; t < LL / 2; t += 512) {
        int i = ((t & ~(stride - 1)) << 1) | (t & (stride - 1));
        ce_desc(sh.key, i, i + stride, (i & size) == 0);
      }
      SBAR_LDS();
    }
    for (int stride = 128; stride > 0; stride >>= 1) {
#pragma unroll
      for (int pp = 0; pp < 2; ++pp) {
        int p = w * 128 + pp * 64 + lane;
        int i = ((p & ~(stride - 1)) << 1) | (p & (stride - 1));
        ce_desc(sh.key, i, i + stride, (i & size) == 0);
      }
      __builtin_amdgcn_wave_barrier();
    }
    SBAR_LDS();
  }

  // --- extract perm into registers; write mask_t ---
  const int cnt = wcnt[0] + wcnt[1] + wcnt[2] + wcnt[3] +
                  wcnt[4] + wcnt[5] + wcnt[6] + wcnt[7];
  const int maxlen = cnt > 1 ? cnt : 1;              // jnp.maximum(count, 1)
  const unsigned ordNeg1 = ~__float_as_uint(-1.0f);  // ord(-1.0)
  int sv[4]; float mf[4];
#pragma unroll
  for (int k = 0; k < 4; ++k) {
    const int j = tid * 4 + k;
    unsigned long long k2 = sh.key[KIDX(j)];
    int idx = (LL - 1) - (int)(unsigned)(k2 & 0xFFFFFFFFull);
    bool masked = ((unsigned)(k2 >> 32)) == ordNeg1;
    bool keep = j < maxlen;
    sv[k] = idx | (keep ? (1 << 12) : 0);
    mf[k] = (keep && masked) ? 1.0f : 0.0f;
  }
  const int4 s = make_int4(sv[0], sv[1], sv[2], sv[3]);
  ((float4*)(mo + (size_t)b * LL))[tid] =
      make_float4(mf[0], mf[1], mf[2], mf[3]);
  SBAR_LDS();  // all key[] reads done before ring slots get written

  // Zero-tail fast path: thread's whole j-range is zero iff 4*tid >= maxlen.
  const bool anykeep = (4 * tid) < maxlen;

#define GATHER1(buf, dst) do { \
    if (anykeep) { \
      float4 o; \
      o.x = (s.x & (1 << 12)) ? (buf)[s.x & 0x7FF] : 0.0f; \
      o.y = (s.y & (1 << 12)) ? (buf)[s.y & 0x7FF] : 0.0f; \
      o.z = (s.z & (1 << 12)) ? (buf)[s.z & 0x7FF] : 0.0f; \
      o.w = (s.w & (1 << 12)) ? (buf)[s.w & 0x7FF] : 0.0f; \
      ((float4*)(dst))[tid] = o; \
    } else { \
      ((float4*)(dst))[tid] = make_float4(0.0f, 0.0f, 0.0f, 0.0f); \
    } \
  } while (0)

  // Quad: ds_write 4 rows from named regs, ONE barrier, reload regs with
  // rows +16, gather+store the 4 rows.
#define QUAD(qq, RA, RB, RC, RD) do { \
    constexpr int r0 = 4 * (qq); \
    constexpr int s0 = (4 * (qq)) & 7; \
    ((float4*)&sh.ring[s0 + 0][0])[tid] = RA; \
    ((float4*)&sh.ring[s0 + 1][0])[tid] = RB; \
    ((float4*)&sh.ring[s0 + 2][0])[tid] = RC; \
    ((float4*)&sh.ring[s0 + 3][0])[tid] = RD; \
    SBAR_LDS(); \
    if constexpr (r0 + 16 < NR) RA = ((const float4*)SRCROW(r0 + 16))[tid]; \
    if constexpr (r0 + 17 < NR) RB = ((const float4*)SRCROW(r0 + 17))[tid]; \
    if constexpr (r0 + 18 < NR) RC = ((const float4*)SRCROW(r0 + 18))[tid]; \
    if constexpr (r0 + 19 < NR) RD = ((const float4*)SRCROW(r0 + 19))[tid]; \
    GATHER1(&sh.ring[s0 + 0][0], DSTROW(r0 + 0)); \
    GATHER1(&sh.ring[s0 + 1][0], DSTROW(r0 + 1)); \
    GATHER1(&sh.ring[s0 + 2][0], DSTROW(r0 + 2)); \
    GATHER1(&sh.ring[s0 + 3][0], DSTROW(r0 + 3)); \
  } while (0)

  QUAD(0,  A0,  A1,  A2,  A3);
  QUAD(1,  A4,  A5,  A6,  A7);
  QUAD(2,  A8,  A9,  A10, A11);
  QUAD(3,  A12, A13, A14, A15);
  QUAD(4,  A0,  A1,  A2,  A3);
  QUAD(5,  A4,  A5,  A6,  A7);
  QUAD(6,  A8,  A9,  A10, A11);
  QUAD(7,  A12, A13, A14, A15);
  QUAD(8,  A0,  A1,  A2,  A3);
  QUAD(9,  A4,  A5,  A6,  A7);
  QUAD(10, A8,  A9,  A10, A11);
  QUAD(11, A12, A13, A14, A15);
  QUAD(12, A0,  A1,  A2,  A3);
  QUAD(13, A4,  A5,  A6,  A7);
  QUAD(14, A8,  A9,  A10, A11);
  QUAD(15, A12, A13, A14, A15);
  QUAD(16, A0,  A1,  A2,  A3);
#undef QUAD
#undef GATHER1
#undef SRCROW
#undef DSTROW
}

extern "C" void kernel_launch(void* const* d_in, const int* in_sizes, int n_in,
                              void* d_out, int out_size, void* d_ws, size_t ws_size,
                              hipStream_t stream) {
  const float* x    = (const float*)d_in[0];
  const float* v    = (const float*)d_in[1];
  const void*  mask = d_in[2];
  const float* rnd  = (const float*)d_in[3];

  float* xo = (float*)d_out;                  // B*C*L
  float* vo = xo + (size_t)BB * CC * LL;      // B*CV*L
  float* mo = vo + (size_t)BB * CVV * LL;     // B*1*L

  trimmer_kernel<<<BB, 512, 0, stream>>>(x, v, mask, rnd, xo, vo, mo);
}